// Round 3
// baseline (760.361 us; speedup 1.0000x reference)
//
#include <hip/hip_runtime.h>
#include <hip/hip_bf16.h>

using bf16 = __hip_bfloat16;
typedef __bf16 bf16x8 __attribute__((ext_vector_type(8)));
typedef __bf16 bf16x4 __attribute__((ext_vector_type(4)));
typedef float f32x4 __attribute__((ext_vector_type(4)));

// async global->LDS, 16B per lane. LDS dest must be wave-uniform base + lane*16.
__device__ __forceinline__ void async16(const void* g, void* l) {
    __builtin_amdgcn_global_load_lds((const __attribute__((address_space(1))) void*)g,
                                     (__attribute__((address_space(3))) void*)l, 16, 0, 0);
}
__device__ __forceinline__ bf16x8 ld8(const bf16* p) {
    return *reinterpret_cast<const bf16x8*>(p);
}
__device__ __forceinline__ unsigned short bfbits(float f) {
    bf16 h = __float2bfloat16(f);
    return *reinterpret_cast<unsigned short*>(&h);
}

// ---------------- prep kernels ----------------

// fp32 [4096][1024] x3 -> bf16, straight cast
__global__ __launch_bounds__(256) void cast_kernel(const float* __restrict__ q, const float* __restrict__ k,
                                                   const float* __restrict__ v, bf16* __restrict__ dst) {
    int z = blockIdx.z;
    const float* src = (z == 0) ? q : (z == 1) ? k : v;
    bf16* d = dst + (size_t)z * 4194304u;
    size_t i = ((size_t)blockIdx.x * 256 + threadIdx.x) * 4;
    float4 f = *(const float4*)(src + i);
    ushort4 pk = make_ushort4(bfbits(f.x), bfbits(f.y), bfbits(f.z), bfbits(f.w));
    *(ushort4*)(d + i) = pk;
}

// W[16][1024][64] fp32 -> Wt[(n*64+d)][h] bf16 (per-head transpose)
__global__ __launch_bounds__(256) void wt_kernel(const float* __restrict__ wq, const float* __restrict__ wk,
                                                 const float* __restrict__ wv, bf16* __restrict__ wt) {
    int z = blockIdx.z;
    const float* W = (z == 0) ? wq : (z == 1) ? wk : wv;
    bf16* Wt = wt + (size_t)z * (1024u * 1024u);
    int n = blockIdx.y, h0 = blockIdx.x * 64;
    __shared__ float tile[64][65];
    int t = threadIdx.x, row = t >> 2, cq = t & 3;
#pragma unroll
    for (int u = 0; u < 4; u++) {
        int col = cq * 16 + u * 4;
        float4 f = *(const float4*)(W + (size_t)(n * 1024 + h0 + row) * 64 + col);
        tile[row][col] = f.x; tile[row][col + 1] = f.y; tile[row][col + 2] = f.z; tile[row][col + 3] = f.w;
    }
    __syncthreads();
#pragma unroll
    for (int u = 0; u < 4; u++) {
        int hl = cq * 16 + u * 4;  // row here = d on write side
        ushort4 pk = make_ushort4(bfbits(tile[hl][row]), bfbits(tile[hl + 1][row]),
                                  bfbits(tile[hl + 2][row]), bfbits(tile[hl + 3][row]));
        *(ushort4*)(Wt + (size_t)(n * 64 + row) * 1024 + h0 + hl) = pk;
    }
}

// Wo[1024][1024] fp32 -> Wot[j][h] bf16 (transpose)
__global__ __launch_bounds__(256) void wo_kernel(const float* __restrict__ Wo, bf16* __restrict__ Wot) {
    int h0 = blockIdx.x * 64, j0 = blockIdx.y * 64;
    __shared__ float tile[64][65];
    int t = threadIdx.x, row = t >> 2, cq = t & 3;
#pragma unroll
    for (int u = 0; u < 4; u++) {
        int col = cq * 16 + u * 4;
        float4 f = *(const float4*)(Wo + (size_t)(h0 + row) * 1024 + j0 + col);
        tile[row][col] = f.x; tile[row][col + 1] = f.y; tile[row][col + 2] = f.z; tile[row][col + 3] = f.w;
    }
    __syncthreads();
#pragma unroll
    for (int u = 0; u < 4; u++) {
        int hl = cq * 16 + u * 4;
        ushort4 pk = make_ushort4(bfbits(tile[hl][row]), bfbits(tile[hl + 1][row]),
                                  bfbits(tile[hl + 2][row]), bfbits(tile[hl + 3][row]));
        *(ushort4*)(Wot + (size_t)(j0 + row) * 1024 + h0 + hl) = pk;
    }
}

// ---------------- projection GEMM ----------------
// z in {0,1,2}: q,k,v.  C[4096][1024] = X[4096][1024] @ W'[1024][1024] (B given as rows of W'^T)
// q,k -> [b][n][s][d] bf16 ; v -> [b][n][d][s] bf16 (transposed for P@V B-operand)
// q is pre-scaled by 0.125*log2(e) so attn can use a bare exp2.
__global__ __launch_bounds__(256) void proj_kernel(const bf16* __restrict__ Xall, const bf16* __restrict__ Wall,
                                                   bf16* __restrict__ qb, bf16* __restrict__ kb,
                                                   bf16* __restrict__ vt) {
    int z = blockIdx.z;
    const bf16* X = Xall + (size_t)z * (4096u * 1024u);
    const bf16* W = Wall + (size_t)z * (1024u * 1024u);
    __shared__ bf16 sA[128 * 64];
    __shared__ bf16 sB[128 * 64];
    int t = threadIdx.x, lane = t & 63, q4 = lane >> 4, cl = lane & 15, w = t >> 6;
    int wm = (w >> 1) * 64, wn = (w & 1) * 64;
    int m0 = blockIdx.x * 128, n0 = blockIdx.y * 128;
    f32x4 acc[4][4] = {};
    for (int k0 = 0; k0 < 1024; k0 += 64) {
#pragma unroll
        for (int it = 0; it < 4; it++) {
            int j = it * 256 + t;
            int row = j >> 3, sl = j & 7, g = sl ^ (row & 7);  // XOR swizzle of 16B chunks
            async16(X + (size_t)(m0 + row) * 1024 + k0 + g * 8, sA + j * 8);
            async16(W + (size_t)(n0 + row) * 1024 + k0 + g * 8, sB + j * 8);
        }
        __syncthreads();
#pragma unroll
        for (int ks = 0; ks < 2; ks++) {
            bf16x8 af[4], bfr[4];
#pragma unroll
            for (int mi = 0; mi < 4; mi++) {
                int row = wm + mi * 16 + cl;
                af[mi] = ld8(sA + row * 64 + ((ks * 4 + q4) ^ (row & 7)) * 8);
            }
#pragma unroll
            for (int ni = 0; ni < 4; ni++) {
                int row = wn + ni * 16 + cl;
                bfr[ni] = ld8(sB + row * 64 + ((ks * 4 + q4) ^ (row & 7)) * 8);
            }
#pragma unroll
            for (int mi = 0; mi < 4; mi++)
#pragma unroll
                for (int ni = 0; ni < 4; ni++)
                    acc[mi][ni] = __builtin_amdgcn_mfma_f32_16x16x32_bf16(af[mi], bfr[ni], acc[mi][ni], 0, 0, 0);
        }
        __syncthreads();
    }
    if (z < 2) {
        bf16* dst = (z == 0) ? qb : kb;
        float qs = (z == 0) ? 0.18033688011112042f : 1.0f;  // 0.125 * log2(e) folded into q
#pragma unroll
        for (int mi = 0; mi < 4; mi++)
#pragma unroll
            for (int ni = 0; ni < 4; ni++) {
                int col = n0 + wn + ni * 16 + cl;
                int hn = col >> 6, dd = col & 63;
#pragma unroll
                for (int i = 0; i < 4; i++) {
                    int row = m0 + wm + mi * 16 + q4 * 4 + i;  // C/D: col=lane&15, row=quad*4+reg
                    int b = row >> 11, s = row & 2047;
                    dst[(size_t)((b * 16 + hn) * 2048 + s) * 64 + dd] = __float2bfloat16(acc[mi][ni][i] * qs);
                }
            }
    } else {
#pragma unroll
        for (int mi = 0; mi < 4; mi++)
#pragma unroll
            for (int ni = 0; ni < 4; ni++) {
                int col = n0 + wn + ni * 16 + cl;
                int hn = col >> 6, dd = col & 63;
                int row0 = m0 + wm + mi * 16 + q4 * 4;
                int b = row0 >> 11, s = row0 & 2047;
                ushort4 pk = make_ushort4(bfbits(acc[mi][ni][0]), bfbits(acc[mi][ni][1]),
                                          bfbits(acc[mi][ni][2]), bfbits(acc[mi][ni][3]));
                *(ushort4*)(vt + (size_t)((b * 16 + hn) * 64 + dd) * 2048 + s) = pk;
            }
    }
}

// ---------------- fused attention ----------------
// One wg per (b*16+n, 64 q-rows). blockIdx.x = head (keeps one head's K/V on one XCD L2),
// blockIdx.y = q-block. Pass1: row-sums of exp2(q'k) with K double-buffered, 1 barrier/chunk.
// Pass2: recompute P into LDS (bf16), PV-accumulate, write normalized attn straight from LDS
// with coalesced float4 NT stores; counted vmcnt(4) keeps stores in flight across barriers.
__global__ __launch_bounds__(256) void attn_kernel(const bf16* __restrict__ qb, const bf16* __restrict__ kb,
                                                   const bf16* __restrict__ vt, bf16* __restrict__ cc,
                                                   float* __restrict__ attn) {
    __shared__ bf16 sQP[64 * 64];     // Q during prologue, P tile in pass 2
    __shared__ bf16 sKb[64 * 64];     // pass1: dbuf half A; pass2: K (single buffer)
    __shared__ bf16 sVb[2][64 * 64];  // pass1: [0]=dbuf half B; pass2: V double buffer
    __shared__ float srow[64];
    __shared__ float sinv[64];
    int t = threadIdx.x, lane = t & 63, q4 = lane >> 4, cl = lane & 15, w = t >> 6;
    int bn = blockIdx.x;
    int s0 = blockIdx.y * 64;
    const bf16* qh = qb + (size_t)bn * 2048 * 64;
    const bf16* kh = kb + (size_t)bn * 2048 * 64;
    const bf16* vh = vt + (size_t)bn * 64 * 2048;
    float* ah = attn + (size_t)bn * 2048 * 2048;

    if (t < 64) srow[t] = 0.f;
    // stage Q + K chunk 0
#pragma unroll
    for (int it = 0; it < 2; it++) {
        int j = it * 256 + t;
        int row = j >> 3, sl = j & 7, g = sl ^ (row & 7);
        async16(qh + (size_t)(s0 + row) * 64 + g * 8, sQP + j * 8);
        async16(kh + (size_t)row * 64 + g * 8, sKb + j * 8);
    }
    __syncthreads();

    // hoist Q fragments (loop-invariant across all chunks, both passes)
    bf16x8 aq[4][2];
#pragma unroll
    for (int mi = 0; mi < 4; mi++)
#pragma unroll
        for (int ks = 0; ks < 2; ks++) {
            int row = mi * 16 + cl;
            aq[mi][ks] = ld8(sQP + row * 64 + ((ks * 4 + q4) ^ (row & 7)) * 8);
        }

    // ---- pass 1: row sums ----
    float rs[4][4] = {};
    for (int ch = 0; ch < 32; ch++) {
        const bf16* kcur = (ch & 1) ? sVb[0] : sKb;
        bf16* knxt = (ch & 1) ? sKb : sVb[0];
        if (ch < 31) {
#pragma unroll
            for (int it = 0; it < 2; it++) {
                int j = it * 256 + t;
                int row = j >> 3, sl = j & 7, g = sl ^ (row & 7);
                async16(kh + (size_t)((ch + 1) * 64 + row) * 64 + g * 8, knxt + j * 8);
            }
        }
        bf16x8 bk[2];
#pragma unroll
        for (int ks = 0; ks < 2; ks++) {
            int row = w * 16 + cl;
            bk[ks] = ld8(kcur + row * 64 + ((ks * 4 + q4) ^ (row & 7)) * 8);
        }
#pragma unroll
        for (int mi = 0; mi < 4; mi++) {
            f32x4 sa = {0.f, 0.f, 0.f, 0.f};
            sa = __builtin_amdgcn_mfma_f32_16x16x32_bf16(aq[mi][0], bk[0], sa, 0, 0, 0);
            sa = __builtin_amdgcn_mfma_f32_16x16x32_bf16(aq[mi][1], bk[1], sa, 0, 0, 0);
#pragma unroll
            for (int i = 0; i < 4; i++) rs[mi][i] += exp2f(sa[i]);
        }
        __syncthreads();  // drains prefetch (hidden under compute) + frees kcur for overwrite
    }
#pragma unroll
    for (int mi = 0; mi < 4; mi++)
#pragma unroll
        for (int i = 0; i < 4; i++) {
            float v = rs[mi][i];
            v += __shfl_xor(v, 1);
            v += __shfl_xor(v, 2);
            v += __shfl_xor(v, 4);
            v += __shfl_xor(v, 8);
            if (cl == 0) atomicAdd(&srow[mi * 16 + q4 * 4 + i], v);
        }
    __syncthreads();
    if (t < 64) sinv[t] = 1.0f / srow[t];
    __syncthreads();
    float invC[4];
#pragma unroll
    for (int i = 0; i < 4; i++) invC[i] = sinv[w * 16 + q4 * 4 + i];

    // ---- pass 2: P, attn write, PV ----
    // prologue: K(0) + V(0)
#pragma unroll
    for (int it = 0; it < 2; it++) {
        int j = it * 256 + t;
        int row = j >> 3, sl = j & 7, g = sl ^ (row & 7);
        async16(kh + (size_t)row * 64 + g * 8, sKb + j * 8);
        async16(vh + (size_t)row * 2048 + g * 8, sVb[0] + j * 8);
    }
    __syncthreads();

    f32x4 ctx[4] = {};
    for (int ch = 0; ch < 32; ch++) {
        int cur = ch & 1;
        // prefetch V(ch+1) into the other V buffer (drained at this chunk's end barrier)
        if (ch < 31) {
#pragma unroll
            for (int it = 0; it < 2; it++) {
                int j = it * 256 + t;
                int row = j >> 3, sl = j & 7, g = sl ^ (row & 7);
                async16(vh + (size_t)row * 2048 + (ch + 1) * 64 + g * 8, sVb[cur ^ 1] + j * 8);
            }
        }
        __builtin_amdgcn_sched_barrier(0);
        // QK^T on K(ch), P -> LDS (bf16, unnormalized)
        bf16x8 bk[2];
#pragma unroll
        for (int ks = 0; ks < 2; ks++) {
            int row = w * 16 + cl;
            bk[ks] = ld8(sKb + row * 64 + ((ks * 4 + q4) ^ (row & 7)) * 8);
        }
        int c2 = w * 16 + cl;
#pragma unroll
        for (int mi = 0; mi < 4; mi++) {
            f32x4 sa = {0.f, 0.f, 0.f, 0.f};
            sa = __builtin_amdgcn_mfma_f32_16x16x32_bf16(aq[mi][0], bk[0], sa, 0, 0, 0);
            sa = __builtin_amdgcn_mfma_f32_16x16x32_bf16(aq[mi][1], bk[1], sa, 0, 0, 0);
#pragma unroll
            for (int i = 0; i < 4; i++) {
                float p = exp2f(sa[i]);
                int r = mi * 16 + q4 * 4 + i;
                sQP[r * 64 + ((c2 >> 3) ^ (r & 7)) * 8 + (c2 & 7)] = __float2bfloat16(p);
            }
        }
        // mid barrier: P visible; LDS-only drain, async V stays in flight
        asm volatile("s_waitcnt lgkmcnt(0)" ::: "memory");
        __builtin_amdgcn_sched_barrier(0);
        __builtin_amdgcn_s_barrier();
        // K(ch) fully consumed by all waves -> stage K(ch+1) into the same buffer
        if (ch < 31) {
#pragma unroll
            for (int it = 0; it < 2; it++) {
                int j = it * 256 + t;
                int row = j >> 3, sl = j & 7, g = sl ^ (row & 7);
                async16(kh + (size_t)((ch + 1) * 64 + row) * 64 + g * 8, sKb + j * 8);
            }
        }
        __builtin_amdgcn_sched_barrier(0);
        // PV on V(ch)
        const bf16* vcur = sVb[cur];
#pragma unroll
        for (int ks = 0; ks < 2; ks++) {
            int rp = w * 16 + cl;  // wave owns 16 ctx rows
            bf16x8 ap = ld8(sQP + rp * 64 + ((ks * 4 + q4) ^ (rp & 7)) * 8);
#pragma unroll
            for (int ni = 0; ni < 4; ni++) {
                int rv = ni * 16 + cl;
                bf16x8 bv = ld8(vcur + rv * 64 + ((ks * 4 + q4) ^ (rv & 7)) * 8);
                ctx[ni] = __builtin_amdgcn_mfma_f32_16x16x32_bf16(ap, bv, ctx[ni], 0, 0, 0);
            }
        }
        // normalized attn tile straight from LDS P: 4 coalesced 16B NT stores/thread
#pragma unroll
        for (int it = 0; it < 4; it++) {
            int j = it * 256 + t;
            int row = j >> 4, qc = j & 15;
            bf16x4 p4 = *reinterpret_cast<const bf16x4*>(sQP + row * 64 + ((qc >> 1) ^ (row & 7)) * 8 + (qc & 1) * 4);
            float inv = sinv[row];
            f32x4 o = {(float)p4[0] * inv, (float)p4[1] * inv, (float)p4[2] * inv, (float)p4[3] * inv};
            __builtin_nontemporal_store(o, reinterpret_cast<f32x4*>(ah + (size_t)(s0 + row) * 2048 + ch * 64 + qc * 4));
        }
        // end barrier: drain the 4 async (V+K prefetch) instrs, leave the 4 stores in flight
        asm volatile("s_waitcnt vmcnt(4) lgkmcnt(0)" ::: "memory");
        __builtin_amdgcn_sched_barrier(0);
        __builtin_amdgcn_s_barrier();
    }
    int b = bn >> 4, n = bn & 15;
#pragma unroll
    for (int ni = 0; ni < 4; ni++)
#pragma unroll
        for (int i = 0; i < 4; i++) {
            int sg = s0 + w * 16 + q4 * 4 + i;
            int dd = ni * 16 + cl;
            cc[(size_t)(b * 2048 + sg) * 1024 + n * 64 + dd] = __float2bfloat16(ctx[ni][i] * invC[i]);
        }
}

// ---------------- output GEMM ----------------
__global__ __launch_bounds__(256) void out_kernel(const bf16* __restrict__ A, const bf16* __restrict__ W,
                                                  float* __restrict__ out) {
    __shared__ bf16 sA[128 * 64];
    __shared__ bf16 sB[128 * 64];
    int t = threadIdx.x, lane = t & 63, q4 = lane >> 4, cl = lane & 15, w = t >> 6;
    int wm = (w >> 1) * 64, wn = (w & 1) * 64;
    int m0 = blockIdx.x * 128, n0 = blockIdx.y * 128;
    f32x4 acc[4][4] = {};
    for (int k0 = 0; k0 < 1024; k0 += 64) {
#pragma unroll
        for (int it = 0; it < 4; it++) {
            int j = it * 256 + t;
            int row = j >> 3, sl = j & 7, g = sl ^ (row & 7);
            async16(A + (size_t)(m0 + row) * 1024 + k0 + g * 8, sA + j * 8);
            async16(W + (size_t)(n0 + row) * 1024 + k0 + g * 8, sB + j * 8);
        }
        __syncthreads();
#pragma unroll
        for (int ks = 0; ks < 2; ks++) {
            bf16x8 af[4], bfr[4];
#pragma unroll
            for (int mi = 0; mi < 4; mi++) {
                int row = wm + mi * 16 + cl;
                af[mi] = ld8(sA + row * 64 + ((ks * 4 + q4) ^ (row & 7)) * 8);
            }
#pragma unroll
            for (int ni = 0; ni < 4; ni++) {
                int row = wn + ni * 16 + cl;
                bfr[ni] = ld8(sB + row * 64 + ((ks * 4 + q4) ^ (row & 7)) * 8);
            }
#pragma unroll
            for (int mi = 0; mi < 4; mi++)
#pragma unroll
                for (int ni = 0; ni < 4; ni++)
                    acc[mi][ni] = __builtin_amdgcn_mfma_f32_16x16x32_bf16(af[mi], bfr[ni], acc[mi][ni], 0, 0, 0);
        }
        __syncthreads();
    }
#pragma unroll
    for (int mi = 0; mi < 4; mi++)
#pragma unroll
        for (int ni = 0; ni < 4; ni++) {
            int col = n0 + wn + ni * 16 + cl;
#pragma unroll
            for (int i = 0; i < 4; i++) {
                int row = m0 + wm + mi * 16 + q4 * 4 + i;
                out[(size_t)row * 1024 + col] = acc[mi][ni][i];
            }
        }
}

extern "C" void kernel_launch(void* const* d_in, const int* in_sizes, int n_in,
                              void* d_out, int out_size, void* d_ws, size_t ws_size,
                              hipStream_t stream) {
    const float* query = (const float*)d_in[0];
    const float* key = (const float*)d_in[1];
    const float* value = (const float*)d_in[2];
    const float* Wq = (const float*)d_in[3];
    const float* Wk = (const float*)d_in[4];
    const float* Wv = (const float*)d_in[5];
    const float* Wo = (const float*)d_in[6];
    float* out = (float*)d_out;
    float* attn = out + 4194304;  // (out, attn) concatenated flat

    char* w = (char*)d_ws;  // 56 MiB used
    bf16* Xbf = (bf16*)(w);                        // 3 x [4096][1024] bf16  (24 MiB) — dead after proj
    bf16* ccb = (bf16*)(w);                        // concat [4096][1024]    (8 MiB)  — aliases Xbf
    bf16* Wt = (bf16*)(w + (24u << 20));           // 3 x [1024][1024] bf16  (6 MiB)
    bf16* Wot = (bf16*)(w + (30u << 20));          // [1024][1024] bf16      (2 MiB)
    bf16* qbuf = (bf16*)(w + (32u << 20));         // [b][n][s][d] bf16      (8 MiB) pre-scaled by 0.125*log2e
    bf16* kbuf = (bf16*)(w + (40u << 20));         // [b][n][s][d] bf16      (8 MiB)
    bf16* vtb = (bf16*)(w + (48u << 20));          // [b][n][d][s] bf16      (8 MiB)

    cast_kernel<<<dim3(4096, 1, 3), 256, 0, stream>>>(query, key, value, Xbf);
    wt_kernel<<<dim3(16, 16, 3), 256, 0, stream>>>(Wq, Wk, Wv, Wt);
    wo_kernel<<<dim3(16, 16), 256, 0, stream>>>(Wo, Wot);
    proj_kernel<<<dim3(32, 8, 3), 256, 0, stream>>>(Xbf, Wt, qbuf, kbuf, vtb);
    // blockIdx.x = head: all 32 q-blocks of a head land on one XCD (id%8 const) -> K/V L2-local
    attn_kernel<<<dim3(32, 32), 256, 0, stream>>>(qbuf, kbuf, vtb, ccb, attn);
    out_kernel<<<dim3(32, 8), 256, 0, stream>>>(ccb, Wot, out);
}

// Round 4
// 755.355 us; speedup vs baseline: 1.0066x; 1.0066x over previous
//
#include <hip/hip_runtime.h>
#include <hip/hip_bf16.h>

using bf16 = __hip_bfloat16;
typedef __bf16 bf16x8 __attribute__((ext_vector_type(8)));
typedef __bf16 bf16x4 __attribute__((ext_vector_type(4)));
typedef float f32x4 __attribute__((ext_vector_type(4)));

// async global->LDS, 16B per lane. LDS dest must be wave-uniform base + lane*16.
__device__ __forceinline__ void async16(const void* g, void* l) {
    __builtin_amdgcn_global_load_lds((const __attribute__((address_space(1))) void*)g,
                                     (__attribute__((address_space(3))) void*)l, 16, 0, 0);
}
__device__ __forceinline__ bf16x8 ld8(const bf16* p) {
    return *reinterpret_cast<const bf16x8*>(p);
}
__device__ __forceinline__ unsigned short bfbits(float f) {
    bf16 h = __float2bfloat16(f);
    return *reinterpret_cast<unsigned short*>(&h);
}

// ---------------- prep kernels ----------------

// fp32 [4096][1024] x3 -> bf16, straight cast
__global__ __launch_bounds__(256) void cast_kernel(const float* __restrict__ q, const float* __restrict__ k,
                                                   const float* __restrict__ v, bf16* __restrict__ dst) {
    int z = blockIdx.z;
    const float* src = (z == 0) ? q : (z == 1) ? k : v;
    bf16* d = dst + (size_t)z * 4194304u;
    size_t i = ((size_t)blockIdx.x * 256 + threadIdx.x) * 4;
    float4 f = *(const float4*)(src + i);
    ushort4 pk = make_ushort4(bfbits(f.x), bfbits(f.y), bfbits(f.z), bfbits(f.w));
    *(ushort4*)(d + i) = pk;
}

// W[16][1024][64] fp32 -> Wt[(n*64+d)][h] bf16 (per-head transpose)
__global__ __launch_bounds__(256) void wt_kernel(const float* __restrict__ wq, const float* __restrict__ wk,
                                                 const float* __restrict__ wv, bf16* __restrict__ wt) {
    int z = blockIdx.z;
    const float* W = (z == 0) ? wq : (z == 1) ? wk : wv;
    bf16* Wt = wt + (size_t)z * (1024u * 1024u);
    int n = blockIdx.y, h0 = blockIdx.x * 64;
    __shared__ float tile[64][65];
    int t = threadIdx.x, row = t >> 2, cq = t & 3;
#pragma unroll
    for (int u = 0; u < 4; u++) {
        int col = cq * 16 + u * 4;
        float4 f = *(const float4*)(W + (size_t)(n * 1024 + h0 + row) * 64 + col);
        tile[row][col] = f.x; tile[row][col + 1] = f.y; tile[row][col + 2] = f.z; tile[row][col + 3] = f.w;
    }
    __syncthreads();
#pragma unroll
    for (int u = 0; u < 4; u++) {
        int hl = cq * 16 + u * 4;  // row here = d on write side
        ushort4 pk = make_ushort4(bfbits(tile[hl][row]), bfbits(tile[hl + 1][row]),
                                  bfbits(tile[hl + 2][row]), bfbits(tile[hl + 3][row]));
        *(ushort4*)(Wt + (size_t)(n * 64 + row) * 1024 + h0 + hl) = pk;
    }
}

// Wo[1024][1024] fp32 -> Wot[j][h] bf16 (transpose)
__global__ __launch_bounds__(256) void wo_kernel(const float* __restrict__ Wo, bf16* __restrict__ Wot) {
    int h0 = blockIdx.x * 64, j0 = blockIdx.y * 64;
    __shared__ float tile[64][65];
    int t = threadIdx.x, row = t >> 2, cq = t & 3;
#pragma unroll
    for (int u = 0; u < 4; u++) {
        int col = cq * 16 + u * 4;
        float4 f = *(const float4*)(Wo + (size_t)(h0 + row) * 1024 + j0 + col);
        tile[row][col] = f.x; tile[row][col + 1] = f.y; tile[row][col + 2] = f.z; tile[row][col + 3] = f.w;
    }
    __syncthreads();
#pragma unroll
    for (int u = 0; u < 4; u++) {
        int hl = cq * 16 + u * 4;
        ushort4 pk = make_ushort4(bfbits(tile[hl][row]), bfbits(tile[hl + 1][row]),
                                  bfbits(tile[hl + 2][row]), bfbits(tile[hl + 3][row]));
        *(ushort4*)(Wot + (size_t)(j0 + row) * 1024 + h0 + hl) = pk;
    }
}

// ---------------- projection GEMM ----------------
// z in {0,1,2}: q,k,v.  C[4096][1024] = X[4096][1024] @ W'[1024][1024] (B given as rows of W'^T)
// q,k -> [b][n][s][d] bf16 ; v -> [b][n][d][s] bf16 (transposed for P@V B-operand)
// q is pre-scaled by 0.125*log2(e) so attn can use a bare exp2.
__global__ __launch_bounds__(256) void proj_kernel(const bf16* __restrict__ Xall, const bf16* __restrict__ Wall,
                                                   bf16* __restrict__ qb, bf16* __restrict__ kb,
                                                   bf16* __restrict__ vt) {
    int z = blockIdx.z;
    const bf16* X = Xall + (size_t)z * (4096u * 1024u);
    const bf16* W = Wall + (size_t)z * (1024u * 1024u);
    __shared__ bf16 sA[128 * 64];
    __shared__ bf16 sB[128 * 64];
    int t = threadIdx.x, lane = t & 63, q4 = lane >> 4, cl = lane & 15, w = t >> 6;
    int wm = (w >> 1) * 64, wn = (w & 1) * 64;
    int m0 = blockIdx.x * 128, n0 = blockIdx.y * 128;
    f32x4 acc[4][4] = {};
    for (int k0 = 0; k0 < 1024; k0 += 64) {
#pragma unroll
        for (int it = 0; it < 4; it++) {
            int j = it * 256 + t;
            int row = j >> 3, sl = j & 7, g = sl ^ (row & 7);  // XOR swizzle of 16B chunks
            async16(X + (size_t)(m0 + row) * 1024 + k0 + g * 8, sA + j * 8);
            async16(W + (size_t)(n0 + row) * 1024 + k0 + g * 8, sB + j * 8);
        }
        __syncthreads();
#pragma unroll
        for (int ks = 0; ks < 2; ks++) {
            bf16x8 af[4], bfr[4];
#pragma unroll
            for (int mi = 0; mi < 4; mi++) {
                int row = wm + mi * 16 + cl;
                af[mi] = ld8(sA + row * 64 + ((ks * 4 + q4) ^ (row & 7)) * 8);
            }
#pragma unroll
            for (int ni = 0; ni < 4; ni++) {
                int row = wn + ni * 16 + cl;
                bfr[ni] = ld8(sB + row * 64 + ((ks * 4 + q4) ^ (row & 7)) * 8);
            }
#pragma unroll
            for (int mi = 0; mi < 4; mi++)
#pragma unroll
                for (int ni = 0; ni < 4; ni++)
                    acc[mi][ni] = __builtin_amdgcn_mfma_f32_16x16x32_bf16(af[mi], bfr[ni], acc[mi][ni], 0, 0, 0);
        }
        __syncthreads();
    }
    if (z < 2) {
        bf16* dst = (z == 0) ? qb : kb;
        float qs = (z == 0) ? 0.18033688011112042f : 1.0f;  // 0.125 * log2(e) folded into q
#pragma unroll
        for (int mi = 0; mi < 4; mi++)
#pragma unroll
            for (int ni = 0; ni < 4; ni++) {
                int col = n0 + wn + ni * 16 + cl;
                int hn = col >> 6, dd = col & 63;
#pragma unroll
                for (int i = 0; i < 4; i++) {
                    int row = m0 + wm + mi * 16 + q4 * 4 + i;  // C/D: col=lane&15, row=quad*4+reg
                    int b = row >> 11, s = row & 2047;
                    dst[(size_t)((b * 16 + hn) * 2048 + s) * 64 + dd] = __float2bfloat16(acc[mi][ni][i] * qs);
                }
            }
    } else {
#pragma unroll
        for (int mi = 0; mi < 4; mi++)
#pragma unroll
            for (int ni = 0; ni < 4; ni++) {
                int col = n0 + wn + ni * 16 + cl;
                int hn = col >> 6, dd = col & 63;
                int row0 = m0 + wm + mi * 16 + q4 * 4;
                int b = row0 >> 11, s = row0 & 2047;
                ushort4 pk = make_ushort4(bfbits(acc[mi][ni][0]), bfbits(acc[mi][ni][1]),
                                          bfbits(acc[mi][ni][2]), bfbits(acc[mi][ni][3]));
                *(ushort4*)(vt + (size_t)((b * 16 + hn) * 64 + dd) * 2048 + s) = pk;
            }
    }
}

// ---------------- fused attention ----------------
// One wg per (b*16+n, 64 q-rows); blockIdx.x = head (K/V L2-local per XCD).
// WAVE-LOCAL decomposition: each wave owns 16 q-rows x all 64 k-cols of each chunk.
// -> P tile is wave-private (no cross-wave barrier between QK^T and PV),
// -> row-sums are wave-local butterfly allreduces (no atomics, no barriers),
// -> exactly ONE barrier per chunk (K/V double-buffer flip), counted vmcnt(4)
//    keeps attn NT stores in flight across it.
// LDS: 8K P + 16K Kx2 + 16K Vx2 + 256B sinv = 40.25 KiB -> 3 wg/CU.
__global__ __launch_bounds__(256) void attn_kernel(const bf16* __restrict__ qb, const bf16* __restrict__ kb,
                                                   const bf16* __restrict__ vt, bf16* __restrict__ cc,
                                                   float* __restrict__ attn) {
    __shared__ bf16 sP[64 * 64];      // Q during prologue, then per-wave-private P rows
    __shared__ bf16 sK[2][64 * 64];
    __shared__ bf16 sV[2][64 * 64];
    __shared__ float sinv[64];
    int t = threadIdx.x, lane = t & 63, q4 = lane >> 4, cl = lane & 15, w = t >> 6;
    int bn = blockIdx.x;
    int s0 = blockIdx.y * 64;
    const bf16* qh = qb + (size_t)bn * 2048 * 64;
    const bf16* kh = kb + (size_t)bn * 2048 * 64;
    const bf16* vh = vt + (size_t)bn * 64 * 2048;
    float* ah = attn + (size_t)bn * 2048 * 2048;

    // stage Q + K(0)
#pragma unroll
    for (int it = 0; it < 2; it++) {
        int j = it * 256 + t;
        int row = j >> 3, sl = j & 7, g = sl ^ (row & 7);
        async16(qh + (size_t)(s0 + row) * 64 + g * 8, sP + j * 8);
        async16(kh + (size_t)row * 64 + g * 8, sK[0] + j * 8);
    }
    __syncthreads();

    // hoist own-wave Q rows (w*16+cl) — loop-invariant for both passes
    bf16x8 aq[2];
#pragma unroll
    for (int ks = 0; ks < 2; ks++) {
        int row = w * 16 + cl;
        aq[ks] = ld8(sP + row * 64 + ((ks * 4 + q4) ^ (row & 7)) * 8);
    }

    // ---- pass 1: wave-local row sums of exp2(q'k) ----
    float rs[4] = {0.f, 0.f, 0.f, 0.f};
    for (int ch = 0; ch < 32; ch++) {
        int cur = ch & 1;
        if (ch < 31) {
#pragma unroll
            for (int it = 0; it < 2; it++) {
                int j = it * 256 + t;
                int row = j >> 3, sl = j & 7, g = sl ^ (row & 7);
                async16(kh + (size_t)((ch + 1) * 64 + row) * 64 + g * 8, sK[cur ^ 1] + j * 8);
            }
        }
        __builtin_amdgcn_s_setprio(1);
#pragma unroll
        for (int ni = 0; ni < 4; ni++) {
            f32x4 sa = {0.f, 0.f, 0.f, 0.f};
#pragma unroll
            for (int ks = 0; ks < 2; ks++) {
                int row = ni * 16 + cl;
                bf16x8 bk = ld8(sK[cur] + row * 64 + ((ks * 4 + q4) ^ (row & 7)) * 8);
                sa = __builtin_amdgcn_mfma_f32_16x16x32_bf16(aq[ks], bk, sa, 0, 0, 0);
            }
#pragma unroll
            for (int i = 0; i < 4; i++) rs[i] += exp2f(sa[i]);
        }
        __builtin_amdgcn_s_setprio(0);
        __syncthreads();  // drains K prefetch; frees sK[cur] for next overwrite
    }
    // wave-local allreduce over the 16 lanes sharing each q-row
    float invR[4];
#pragma unroll
    for (int i = 0; i < 4; i++) {
        float v = rs[i];
        v += __shfl_xor(v, 1);
        v += __shfl_xor(v, 2);
        v += __shfl_xor(v, 4);
        v += __shfl_xor(v, 8);
        invR[i] = 1.0f / v;
        if (cl == 0) sinv[w * 16 + q4 * 4 + i] = invR[i];
    }

    // ---- pass 2: P (wave-private), attn write, PV ----
#pragma unroll
    for (int it = 0; it < 2; it++) {
        int j = it * 256 + t;
        int row = j >> 3, sl = j & 7, g = sl ^ (row & 7);
        async16(kh + (size_t)row * 64 + g * 8, sK[0] + j * 8);
        async16(vh + (size_t)row * 2048 + g * 8, sV[0] + j * 8);
    }
    __syncthreads();  // also makes sinv visible (wave-local anyway)

    f32x4 ctx[4] = {};
    for (int ch = 0; ch < 32; ch++) {
        int cur = ch & 1;
        // prefetch K(ch+1)+V(ch+1): full chunk of compute covers the latency
        if (ch < 31) {
#pragma unroll
            for (int it = 0; it < 2; it++) {
                int j = it * 256 + t;
                int row = j >> 3, sl = j & 7, g = sl ^ (row & 7);
                async16(kh + (size_t)((ch + 1) * 64 + row) * 64 + g * 8, sK[cur ^ 1] + j * 8);
                async16(vh + (size_t)row * 2048 + (ch + 1) * 64 + g * 8, sV[cur ^ 1] + j * 8);
            }
        }
        __builtin_amdgcn_sched_barrier(0);
        // QK^T: own 16 q-rows x 64 k-cols
        f32x4 sa[4] = {};
        __builtin_amdgcn_s_setprio(1);
#pragma unroll
        for (int ks = 0; ks < 2; ks++) {
#pragma unroll
            for (int ni = 0; ni < 4; ni++) {
                int row = ni * 16 + cl;
                bf16x8 bk = ld8(sK[cur] + row * 64 + ((ks * 4 + q4) ^ (row & 7)) * 8);
                sa[ni] = __builtin_amdgcn_mfma_f32_16x16x32_bf16(aq[ks], bk, sa[ni], 0, 0, 0);
            }
        }
        __builtin_amdgcn_s_setprio(0);
        // P -> own LDS rows (bf16, unnormalized); wave-private so no barrier
        int r0 = w * 16 + q4 * 4;
#pragma unroll
        for (int ni = 0; ni < 4; ni++) {
            int c2 = ni * 16 + cl;
#pragma unroll
            for (int i = 0; i < 4; i++) {
                float p = exp2f(sa[ni][i]);
                int r = r0 + i;
                sP[r * 64 + ((c2 >> 3) ^ (r & 7)) * 8 + (c2 & 7)] = __float2bfloat16(p);
            }
        }
        asm volatile("s_waitcnt lgkmcnt(0)" ::: "memory");
        __builtin_amdgcn_sched_barrier(0);
        // PV from own P rows
        __builtin_amdgcn_s_setprio(1);
#pragma unroll
        for (int ks = 0; ks < 2; ks++) {
            int rp = w * 16 + cl;
            bf16x8 ap = ld8(sP + rp * 64 + ((ks * 4 + q4) ^ (rp & 7)) * 8);
#pragma unroll
            for (int ni = 0; ni < 4; ni++) {
                int rv = ni * 16 + cl;
                bf16x8 bv = ld8(sV[cur] + rv * 64 + ((ks * 4 + q4) ^ (rv & 7)) * 8);
                ctx[ni] = __builtin_amdgcn_mfma_f32_16x16x32_bf16(ap, bv, ctx[ni], 0, 0, 0);
            }
        }
        __builtin_amdgcn_s_setprio(0);
        // normalized attn tile: own 16 rows, 4 coalesced 16B NT stores/lane
#pragma unroll
        for (int it = 0; it < 4; it++) {
            int idx = it * 64 + lane;
            int rl = idx >> 4, qc = idx & 15;
            int row = w * 16 + rl;
            bf16x4 p4 = *reinterpret_cast<const bf16x4*>(sP + row * 64 + ((qc >> 1) ^ (row & 7)) * 8 + (qc & 1) * 4);
            float inv = sinv[row];
            f32x4 o = {(float)p4[0] * inv, (float)p4[1] * inv, (float)p4[2] * inv, (float)p4[3] * inv};
            __builtin_nontemporal_store(o, reinterpret_cast<f32x4*>(ah + (size_t)(s0 + row) * 2048 + ch * 64 + qc * 4));
        }
        // single per-chunk barrier: drain the 4 prefetch asyncs, leave 4 stores in flight
        if (ch < 31) {
            asm volatile("s_waitcnt vmcnt(4) lgkmcnt(0)" ::: "memory");
            __builtin_amdgcn_sched_barrier(0);
            __builtin_amdgcn_s_barrier();
        }
    }
    int b = bn >> 4, n = bn & 15;
#pragma unroll
    for (int ni = 0; ni < 4; ni++)
#pragma unroll
        for (int i = 0; i < 4; i++) {
            int sg = s0 + w * 16 + q4 * 4 + i;
            int dd = ni * 16 + cl;
            cc[(size_t)(b * 2048 + sg) * 1024 + n * 64 + dd] = __float2bfloat16(ctx[ni][i] * invR[i]);
        }
}

// ---------------- output GEMM ----------------
__global__ __launch_bounds__(256) void out_kernel(const bf16* __restrict__ A, const bf16* __restrict__ W,
                                                  float* __restrict__ out) {
    __shared__ bf16 sA[128 * 64];
    __shared__ bf16 sB[128 * 64];
    int t = threadIdx.x, lane = t & 63, q4 = lane >> 4, cl = lane & 15, w = t >> 6;
    int wm = (w >> 1) * 64, wn = (w & 1) * 64;
    int m0 = blockIdx.x * 128, n0 = blockIdx.y * 128;
    f32x4 acc[4][4] = {};
    for (int k0 = 0; k0 < 1024; k0 += 64) {
#pragma unroll
        for (int it = 0; it < 4; it++) {
            int j = it * 256 + t;
            int row = j >> 3, sl = j & 7, g = sl ^ (row & 7);
            async16(A + (size_t)(m0 + row) * 1024 + k0 + g * 8, sA + j * 8);
            async16(W + (size_t)(n0 + row) * 1024 + k0 + g * 8, sB + j * 8);
        }
        __syncthreads();
#pragma unroll
        for (int ks = 0; ks < 2; ks++) {
            bf16x8 af[4], bfr[4];
#pragma unroll
            for (int mi = 0; mi < 4; mi++) {
                int row = wm + mi * 16 + cl;
                af[mi] = ld8(sA + row * 64 + ((ks * 4 + q4) ^ (row & 7)) * 8);
            }
#pragma unroll
            for (int ni = 0; ni < 4; ni++) {
                int row = wn + ni * 16 + cl;
                bfr[ni] = ld8(sB + row * 64 + ((ks * 4 + q4) ^ (row & 7)) * 8);
            }
#pragma unroll
            for (int mi = 0; mi < 4; mi++)
#pragma unroll
                for (int ni = 0; ni < 4; ni++)
                    acc[mi][ni] = __builtin_amdgcn_mfma_f32_16x16x32_bf16(af[mi], bfr[ni], acc[mi][ni], 0, 0, 0);
        }
        __syncthreads();
    }
#pragma unroll
    for (int mi = 0; mi < 4; mi++)
#pragma unroll
        for (int ni = 0; ni < 4; ni++) {
            int col = n0 + wn + ni * 16 + cl;
#pragma unroll
            for (int i = 0; i < 4; i++) {
                int row = m0 + wm + mi * 16 + q4 * 4 + i;
                out[(size_t)row * 1024 + col] = acc[mi][ni][i];
            }
        }
}

extern "C" void kernel_launch(void* const* d_in, const int* in_sizes, int n_in,
                              void* d_out, int out_size, void* d_ws, size_t ws_size,
                              hipStream_t stream) {
    const float* query = (const float*)d_in[0];
    const float* key = (const float*)d_in[1];
    const float* value = (const float*)d_in[2];
    const float* Wq = (const float*)d_in[3];
    const float* Wk = (const float*)d_in[4];
    const float* Wv = (const float*)d_in[5];
    const float* Wo = (const float*)d_in[6];
    float* out = (float*)d_out;
    float* attn = out + 4194304;  // (out, attn) concatenated flat

    char* w = (char*)d_ws;  // 56 MiB used
    bf16* Xbf = (bf16*)(w);                        // 3 x [4096][1024] bf16  (24 MiB) — dead after proj
    bf16* ccb = (bf16*)(w);                        // concat [4096][1024]    (8 MiB)  — aliases Xbf
    bf16* Wt = (bf16*)(w + (24u << 20));           // 3 x [1024][1024] bf16  (6 MiB)
    bf16* Wot = (bf16*)(w + (30u << 20));          // [1024][1024] bf16      (2 MiB)
    bf16* qbuf = (bf16*)(w + (32u << 20));         // [b][n][s][d] bf16      (8 MiB) pre-scaled by 0.125*log2e
    bf16* kbuf = (bf16*)(w + (40u << 20));         // [b][n][s][d] bf16      (8 MiB)
    bf16* vtb = (bf16*)(w + (48u << 20));          // [b][n][d][s] bf16      (8 MiB)

    cast_kernel<<<dim3(4096, 1, 3), 256, 0, stream>>>(query, key, value, Xbf);
    wt_kernel<<<dim3(16, 16, 3), 256, 0, stream>>>(Wq, Wk, Wv, Wt);
    wo_kernel<<<dim3(16, 16), 256, 0, stream>>>(Wo, Wot);
    proj_kernel<<<dim3(32, 8, 3), 256, 0, stream>>>(Xbf, Wt, qbuf, kbuf, vtb);
    // blockIdx.x = head: all 32 q-blocks of a head land on one XCD (id%8 const) -> K/V L2-local
    attn_kernel<<<dim3(32, 32), 256, 0, stream>>>(qbuf, kbuf, vtb, ccb, attn);
    out_kernel<<<dim3(32, 8), 256, 0, stream>>>(ccb, Wot, out);
}